// Round 1
// baseline (520.823 us; speedup 1.0000x reference)
//
#include <hip/hip_runtime.h>
#include <hip/hip_bf16.h>

// GAT 2-layer + linear head. All fp32.
// N=50000, E=400000 (+N self loops), IN_DIM=128, HEADS=3, HID=64 (HC=192), CLASSES=40.

#define NNODES 50000
#define NEDGES 400000
#define HC 192
#define NHEADS 3
#define HIDC 64
#define NCLS 40

// ---------------- CSR build ----------------

__global__ void hist_kernel(const int* __restrict__ ei, int* __restrict__ deg,
                            int E_, int n) {
    int e = blockIdx.x * blockDim.x + threadIdx.x;
    int ET = E_ + n;
    if (e >= ET) return;
    int d = (e < E_) ? ei[E_ + e] : (e - E_);
    atomicAdd(&deg[d], 1);
}

// single block, 1024 threads: exclusive scan of deg -> row_ptr, row_ptr[n]=total
__global__ __launch_bounds__(1024) void scan_kernel(const int* __restrict__ deg,
                                                    int* __restrict__ rowp, int n) {
    __shared__ int sums[1024];
    int tid = threadIdx.x;
    int per = (n + 1023) >> 10;
    int begin = tid * per;
    int end = begin + per; if (end > n) end = n;
    int s = 0;
    for (int i = begin; i < end && i < n; ++i) s += deg[i];
    sums[tid] = s;
    __syncthreads();
    for (int off = 1; off < 1024; off <<= 1) {
        int v = (tid >= off) ? sums[tid - off] : 0;
        __syncthreads();
        sums[tid] += v;
        __syncthreads();
    }
    int run = (tid == 0) ? 0 : sums[tid - 1];
    for (int i = begin; i < end && i < n; ++i) {
        rowp[i] = run;
        run += deg[i];
    }
    if (tid == 1023) rowp[n] = sums[1023];
}

__global__ void scatter_kernel(const int* __restrict__ ei, const int* __restrict__ rowp,
                               int* __restrict__ cursor, int* __restrict__ esrc,
                               int E_, int n) {
    int e = blockIdx.x * blockDim.x + threadIdx.x;
    int ET = E_ + n;
    if (e >= ET) return;
    int s, d;
    if (e < E_) { s = ei[e]; d = ei[E_ + e]; }
    else        { s = e - E_; d = s; }
    int pos = atomicAdd(&cursor[d], 1);
    esrc[rowp[d] + pos] = s;
}

// ---------------- GEMM: C[n,M] = X[n,K] @ W[M,K]^T (+bias) ----------------
// BM=128, BN=64, BK=16, 256 threads, per-thread 8x4.

template <int K, int M, bool ADD_BIAS>
__global__ __launch_bounds__(256) void gemm_xwt(const float* __restrict__ X,
                                                const float* __restrict__ W,
                                                const float* __restrict__ bias,
                                                float* __restrict__ C, int n) {
    const int BM = 128, BN = 64, BK = 16;
    __shared__ float Xs[BK][BM + 4];
    __shared__ float Ws[BK][BN + 4];
    int bm = blockIdx.x * BM;
    int bn = blockIdx.y * BN;
    int tid = threadIdx.x;
    int tx = tid & 15;   // col group: bn + tx*4 .. +3
    int ty = tid >> 4;   // row group: bm + ty*8 .. +7
    float acc[8][4] = {};

    for (int k0 = 0; k0 < K; k0 += BK) {
        // X tile: 128x16 = 512 float4, 2 per thread
#pragma unroll
        for (int t = 0; t < 2; ++t) {
            int q = tid + t * 256;
            int row = q >> 2;
            int ks = (q & 3) * 4;
            int grow = bm + row;
            float4 v = make_float4(0.f, 0.f, 0.f, 0.f);
            if (grow < n) v = *(const float4*)(X + (size_t)grow * K + k0 + ks);
            Xs[ks + 0][row] = v.x; Xs[ks + 1][row] = v.y;
            Xs[ks + 2][row] = v.z; Xs[ks + 3][row] = v.w;
        }
        // W tile: 64x16 = 256 float4, 1 per thread
        {
            int q = tid;
            int rowm = q >> 2;
            int ks = (q & 3) * 4;
            int gm = bn + rowm;
            float4 v = make_float4(0.f, 0.f, 0.f, 0.f);
            if (gm < M) v = *(const float4*)(W + (size_t)gm * K + k0 + ks);
            Ws[ks + 0][rowm] = v.x; Ws[ks + 1][rowm] = v.y;
            Ws[ks + 2][rowm] = v.z; Ws[ks + 3][rowm] = v.w;
        }
        __syncthreads();
#pragma unroll
        for (int kk = 0; kk < BK; ++kk) {
            float xr[8], wr[4];
#pragma unroll
            for (int i = 0; i < 8; ++i) xr[i] = Xs[kk][ty * 8 + i];
#pragma unroll
            for (int j = 0; j < 4; ++j) wr[j] = Ws[kk][tx * 4 + j];
#pragma unroll
            for (int i = 0; i < 8; ++i)
#pragma unroll
                for (int j = 0; j < 4; ++j) acc[i][j] += xr[i] * wr[j];
        }
        __syncthreads();
    }
#pragma unroll
    for (int i = 0; i < 8; ++i) {
        int grow = bm + ty * 8 + i;
        if (grow >= n) continue;
#pragma unroll
        for (int j = 0; j < 4; ++j) {
            int gcol = bn + tx * 4 + j;
            if (gcol >= M) continue;
            float v = acc[i][j];
            if (ADD_BIAS) v += bias[gcol];
            C[(size_t)grow * M + gcol] = v;
        }
    }
}

// ---------------- attention projections: al/ar [n,3] ----------------
// wave per node; lane = channel.

__global__ __launch_bounds__(256) void attproj_kernel(const float* __restrict__ A,
                                                      const float* __restrict__ attl,
                                                      const float* __restrict__ attr,
                                                      float* __restrict__ al,
                                                      float* __restrict__ ar, int n) {
    int wave = threadIdx.x >> 6;
    int lane = threadIdx.x & 63;
    int node = blockIdx.x * 4 + wave;
    if (node >= n) return;
#pragma unroll
    for (int h = 0; h < NHEADS; ++h) {
        float v = A[(size_t)node * HC + h * HIDC + lane];
        float pl = v * attl[h * HIDC + lane];
        float pr = v * attr[h * HIDC + lane];
#pragma unroll
        for (int off = 32; off; off >>= 1) {
            pl += __shfl_xor(pl, off);
            pr += __shfl_xor(pr, off);
        }
        if (lane == 0) {
            al[node * NHEADS + h] = pl;
            ar[node * NHEADS + h] = pr;
        }
    }
}

// ---------------- aggregation: wave per dst node ----------------

__device__ __forceinline__ float lrelu(float a) { return a > 0.f ? a : 0.2f * a; }

__global__ __launch_bounds__(256) void agg_kernel(const float* __restrict__ hfeat,
                                                  const float* __restrict__ al,
                                                  const float* __restrict__ ar,
                                                  const int* __restrict__ rowp,
                                                  const int* __restrict__ esrc,
                                                  const float* __restrict__ bias,
                                                  float* __restrict__ out, int n) {
    int wave = threadIdx.x >> 6;
    int lane = threadIdx.x & 63;
    int node = blockIdx.x * 4 + wave;
    if (node >= n) return;
    int e0 = rowp[node], e1 = rowp[node + 1];
    float arv0 = ar[node * 3 + 0];
    float arv1 = ar[node * 3 + 1];
    float arv2 = ar[node * 3 + 2];
    // pass 1: per-head max
    float m0 = -1e30f, m1 = -1e30f, m2 = -1e30f;
    for (int e = e0; e < e1; ++e) {
        int s = esrc[e];
        float a0 = lrelu(al[s * 3 + 0] + arv0);
        float a1 = lrelu(al[s * 3 + 1] + arv1);
        float a2 = lrelu(al[s * 3 + 2] + arv2);
        m0 = fmaxf(m0, a0); m1 = fmaxf(m1, a1); m2 = fmaxf(m2, a2);
    }
    // pass 2: weighted accumulate (unnormalized) + denom
    float s0 = 0.f, s1 = 0.f, s2 = 0.f;
    float acc0 = 0.f, acc1 = 0.f, acc2 = 0.f;
    for (int e = e0; e < e1; ++e) {
        int s = esrc[e];
        float w0 = __expf(lrelu(al[s * 3 + 0] + arv0) - m0);
        float w1 = __expf(lrelu(al[s * 3 + 1] + arv1) - m1);
        float w2 = __expf(lrelu(al[s * 3 + 2] + arv2) - m2);
        s0 += w0; s1 += w1; s2 += w2;
        const float* hrow = hfeat + (size_t)s * HC;
        acc0 += w0 * hrow[0 * HIDC + lane];
        acc1 += w1 * hrow[1 * HIDC + lane];
        acc2 += w2 * hrow[2 * HIDC + lane];
    }
    float* orow = out + (size_t)node * HC;
    orow[0 * HIDC + lane] = fmaxf(acc0 / (s0 + 1e-16f) + bias[0 * HIDC + lane], 0.f);
    orow[1 * HIDC + lane] = fmaxf(acc1 / (s1 + 1e-16f) + bias[1 * HIDC + lane], 0.f);
    orow[2 * HIDC + lane] = fmaxf(acc2 / (s2 + 1e-16f) + bias[2 * HIDC + lane], 0.f);
}

// ---------------- launch ----------------

extern "C" void kernel_launch(void* const* d_in, const int* in_sizes, int n_in,
                              void* d_out, int out_size, void* d_ws, size_t ws_size,
                              hipStream_t stream) {
    const float* x     = (const float*)d_in[0];
    const int*   ei    = (const int*)d_in[1];   // [2,E] int
    const float* W1    = (const float*)d_in[2];
    const float* attl1 = (const float*)d_in[3];
    const float* attr1 = (const float*)d_in[4];
    const float* b1    = (const float*)d_in[5];
    const float* W2    = (const float*)d_in[6];
    const float* attl2 = (const float*)d_in[7];
    const float* attr2 = (const float*)d_in[8];
    const float* b2    = (const float*)d_in[9];
    const float* Wo    = (const float*)d_in[10];
    const float* bo    = (const float*)d_in[11];
    float* outp = (float*)d_out;

    const int n = NNODES;
    const int E_ = NEDGES;
    const int ET = E_ + n;

    // workspace layout (~80.4 MB)
    char* ws = (char*)d_ws;
    size_t off = 0;
    auto take = [&](size_t bytes) {
        size_t p = off;
        off += (bytes + 255) & ~(size_t)255;
        return p;
    };
    float* A    = (float*)(ws + take((size_t)n * HC * 4));
    float* B    = (float*)(ws + take((size_t)n * HC * 4));
    float* al   = (float*)(ws + take((size_t)n * 3 * 4));
    float* ar   = (float*)(ws + take((size_t)n * 3 * 4));
    int* rowp   = (int*)(ws + take((size_t)(n + 1) * 4));
    int* deg    = (int*)(ws + take((size_t)n * 4));
    int* cursor = (int*)(ws + take((size_t)n * 4));
    int* esrc   = (int*)(ws + take((size_t)ET * 4));
    (void)ws_size;

    hipMemsetAsync(deg, 0, (size_t)n * 4, stream);
    hipMemsetAsync(cursor, 0, (size_t)n * 4, stream);

    int eb = 256;
    int eg = (ET + eb - 1) / eb;
    hist_kernel<<<eg, eb, 0, stream>>>(ei, deg, E_, n);
    scan_kernel<<<1, 1024, 0, stream>>>(deg, rowp, n);
    scatter_kernel<<<eg, eb, 0, stream>>>(ei, rowp, cursor, esrc, E_, n);

    dim3 gemm_grid((n + 127) / 128, HC / 64);
    dim3 gemm_grid_out((n + 127) / 128, 1);
    int nodeg = (n + 3) / 4;

    // layer 1
    gemm_xwt<128, HC, false><<<gemm_grid, 256, 0, stream>>>(x, W1, nullptr, A, n);
    attproj_kernel<<<nodeg, 256, 0, stream>>>(A, attl1, attr1, al, ar, n);
    agg_kernel<<<nodeg, 256, 0, stream>>>(A, al, ar, rowp, esrc, b1, B, n);
    // layer 2
    gemm_xwt<HC, HC, false><<<gemm_grid, 256, 0, stream>>>(B, W2, nullptr, A, n);
    attproj_kernel<<<nodeg, 256, 0, stream>>>(A, attl2, attr2, al, ar, n);
    agg_kernel<<<nodeg, 256, 0, stream>>>(A, al, ar, rowp, esrc, b2, B, n);
    // output head
    gemm_xwt<HC, NCLS, true><<<gemm_grid_out, 256, 0, stream>>>(B, Wo, bo, outp, n);
}